// Round 7
// baseline (148.958 us; speedup 1.0000x reference)
//
#include <hip/hip_runtime.h>
#include <float.h>

// Problem constants (match reference)
constexpr int H = 1024, W = 1024, C = 128, N_ITER = 8;
constexpr int TPB = 256;          // threads per block
constexpr int TILE = 32;          // 32x32 pixel tile per block
constexpr int PPT = 4;            // pixels (consecutive cols) per thread
constexpr int K = 32;             // atomic shards (contention depth 1024/K = 32)
constexpr int SLOTS = 2 * C;      // 256 accumulator slots
constexpr int NBLK = (H / TILE) * (W / TILE);   // 1024 WORKER blocks (grid = NBLK+1)
constexpr int NCNT = 128;         // barrier arrival counters (depth 8 each)
constexpr int CNT_STRIDE = 16;    // ints between counters (64B apart)
constexpr int ARRIVE_DEPTH = NBLK / NCNT;       // 8
constexpr int NREP = 16;          // publish replicas (spread poll read traffic)
constexpr unsigned SIGNB = 0x80000000u;

// Slice-major workspace: one 56KB slice per iteration
//   [shards K*SLOTS f32 | barCnt NCNT*CNT_STRIDE i32 | clsPub NREP*SLOTS u32]
constexpr int SHARD_WORDS = K * SLOTS;                    // 8192
constexpr int CNT_WORDS   = NCNT * CNT_STRIDE;            // 2048
constexpr int PUB_WORDS   = NREP * SLOTS;                 // 4096
constexpr int SLICE_WORDS = SHARD_WORDS + CNT_WORDS + PUB_WORDS;  // 14336
constexpr int ZERO_PER_BLK = SLICE_WORDS / NBLK;          // 14

// Ledger of locked-in lessons:
// R3: atomic-contention-bound -> 32-way output sharding.
// R4: O(C) dependent-LDS dedup chain -> parallel all-pairs scan.
// R5/6: grid-barrier congestion collapse from ~131K agent-scope pollers;
//   fixed with ONE poller set/block + zero __threadfence (983 -> 99.7us).
// R8: hop compression: batched 32-load shard sum, self-announcing encoded
//   publish (bits^SIGN, poll own data slot), dedup computed ONCE on the
//   aggregator, exported as +inf poisoning (99.7 -> 89.5us).
// R9: regular launch (coop dispatch = ~33us extra) + dedicated aggregator
//   block (89.5 -> 87.5us kernel; 165 -> 141.6 total).
// R10 (this round): detect-term shaving. Per-iter chain is ~9us of serial
//   fabric hops; the reducible parts are detect quantization and fixed cost:
//   (a) worker detect by WAVE 0 ONLY: lane L polls its block's replica
//       slots 4L..4L+3 (4 dword sc0sc1 loads, sleep(1)) and writes decoded
//       coords straight to cls LDS; waves 1-3 wait at the barrier. Kills
//       the max-over-4-waves detect penalty, cuts poll traffic 4x.
//   (b) aggregator: 256 lanes, 2 pollers/counter phase-offset by one
//       sleep quantum -> expected detect -interval/4.
//   (c) slice-major ws; each worker zeroes its 14-word share of slice it+1
//       before its iter-it arrive (agent stores acked by the SAME vmcnt(0)
//       -> ordered before any slice-(it+1) use, which happens only after
//       ALL iter-it arrivals). Host memset: 448KB -> 56KB (slice 0 only).
__device__ __forceinline__ void waitVmem() {
    asm volatile("s_waitcnt vmcnt(0)" ::: "memory");
}

__device__ __forceinline__ float* sliceShards(unsigned* ws, int it) {
    return (float*)(ws + (size_t)it * SLICE_WORDS);
}
__device__ __forceinline__ int* sliceCnt(unsigned* ws, int it) {
    return (int*)(ws + (size_t)it * SLICE_WORDS + SHARD_WORDS);
}
__device__ __forceinline__ unsigned* slicePub(unsigned* ws, int it) {
    return ws + (size_t)it * SLICE_WORDS + SHARD_WORDS + CNT_WORDS;
}

__global__ __launch_bounds__(TPB, 4) void kmeans_fused(
    const float* __restrict__ cur0,        // [SLOTS] input clusters
    const float* __restrict__ heatmap,     // [H,W]
    unsigned* __restrict__ ws,             // [N_ITER][SLICE_WORDS] (slice0 zeroed)
    float* __restrict__ out)               // [SLOTS]
{
    __shared__ __align__(16) float2 cls[C];  // aliased as float[SLOTS]
    __shared__ float2 cand[C];
    __shared__ int    candIdx[C];
    __shared__ float  waveMin[2];
    __shared__ int    waveCnt[2];
    __shared__ float  acc[SLOTS];          // SLOTS == 256 == TPB
    __shared__ unsigned char dupf[C];      // aggregator only

    const int tid = threadIdx.x;
    const int bid = blockIdx.x;

    // ================= dedicated aggregator (no tile work) =================
    if (bid == 0) {
        for (int it = 0; it < N_ITER; ++it) {
            // wake: 2 pollers per counter, phase-staggered by one quantum
            {
                int* cptr = sliceCnt(ws, it) + (tid & (NCNT - 1)) * CNT_STRIDE;
                if (tid >= NCNT) __builtin_amdgcn_s_sleep(1);
                while (__hip_atomic_load(cptr, __ATOMIC_RELAXED,
                                         __HIP_MEMORY_SCOPE_AGENT) < ARRIVE_DEPTH)
                    __builtin_amdgcn_s_sleep(1);
            }
            __syncthreads();

            // sum 32 shards: all bypass loads in flight (~1 round trip);
            // adds keep the exact k-ascending association.
            const float* b = sliceShards(ws, it) + tid;
            float v[K];
#pragma unroll
            for (int k = 0; k < K; ++k)
                v[k] = __hip_atomic_load(b + (size_t)k * SLOTS,
                                         __ATOMIC_RELAXED, __HIP_MEMORY_SCOPE_AGENT);
            float s = 0.0f;
#pragma unroll
            for (int k = 0; k < K; ++k) s += v[k];

            if (it == N_ITER - 1) {        // final: write result, done
                out[tid] = s;
                return;
            }

            // dup scan once (cluster data identical for every block)
            if (tid < C) dupf[tid] = 0;
            ((float*)cls)[tid] = s;
            __syncthreads();
            {
                const int    sdi  = tid & (C - 1);
                const float2 sdme = cls[sdi];
                const int kLo = (tid < C) ? 1 : 33;
#pragma unroll 8
                for (int kk = 0; kk < 32; ++kk) {
                    const int k = kLo + kk;
                    const int j = (sdi + k) & (C - 1);
                    const float2 o = cls[j];
                    if (o.x == sdme.x && o.y == sdme.y)
                        dupf[(sdi + k < C) ? (sdi + k) : sdi] = 1;  // higher idx
                }
            }
            __syncthreads();

            // poison dups with +inf (lowest twin keeps true coords) and
            // publish encoded (always-nonzero) value to NREP replicas
            const float pv = dupf[tid >> 1] ? (float)INFINITY : s;
            const unsigned enc = __float_as_uint(pv) ^ SIGNB;
            unsigned* pb = slicePub(ws, it);
#pragma unroll
            for (int r = 0; r < NREP; ++r)
                __hip_atomic_store(pb + r * SLOTS + tid, enc,
                                   __ATOMIC_RELAXED, __HIP_MEMORY_SCOPE_AGENT);
            // no wait: visibility rides the fabric while we go back to polling
        }
        return;
    }

    // ========================== worker blocks ==========================
    const int wid   = bid - 1;             // tile id 0..1023
    const int tileR = (wid >> 5) * TILE;
    const int tileC = (wid & 31) * TILE;

    // ---- one-time pixel setup (amortized over 8 iters) ----
    const int   rowIn = tid >> 3;                         // 0..31
    const float fr    = (float)(tileR + rowIn);
    const int   col0  = tileC + (tid & 7) * PPT;
    const float4 h4   = *(const float4*)(heatmap + (size_t)(tileR + rowIn) * W + col0);
    float hval[PPT] = { h4.x, h4.y, h4.z, h4.w };
    float colf[PPT];
#pragma unroll
    for (int p = 0; p < PPT; ++p) colf[p] = (float)(col0 + p);

    for (int it = 0; it < N_ITER; ++it) {
        // ---- phase 0: obtain coords into LDS ----
        acc[tid] = 0.0f;
        if (it == 0) {
            ((float*)cls)[tid] = cur0[tid];
        } else if (tid < 64) {
            // wave 0 only: lane L polls its block's replica slots 4L..4L+3
            const unsigned* src = slicePub(ws, it - 1)
                + (wid & (NREP - 1)) * SLOTS + tid * 4;
            unsigned a0, a1, a2, a3;
            for (;;) {
                asm volatile(
                    "global_load_dword %0, %4, off sc0 sc1\n\t"
                    "global_load_dword %1, %5, off sc0 sc1\n\t"
                    "global_load_dword %2, %6, off sc0 sc1\n\t"
                    "global_load_dword %3, %7, off sc0 sc1\n\t"
                    "s_waitcnt vmcnt(0)"
                    : "=&v"(a0), "=&v"(a1), "=&v"(a2), "=&v"(a3)
                    : "v"(src), "v"(src + 1), "v"(src + 2), "v"(src + 3)
                    : "memory");
                const bool ok = (a0 != 0u) & (a1 != 0u) & (a2 != 0u) & (a3 != 0u);
                if (__ballot(ok) == 0xFFFFFFFFFFFFFFFFull) break;
                __builtin_amdgcn_s_sleep(1);
            }
            float* c4 = (float*)cls + tid * 4;
            c4[0] = __uint_as_float(a0 ^ SIGNB);
            c4[1] = __uint_as_float(a1 ^ SIGNB);
            c4[2] = __uint_as_float(a2 ^ SIGNB);
            c4[3] = __uint_as_float(a3 ^ SIGNB);
        }
        __syncthreads();

        // ---- phase 1a: center-distance + wave min (threads 0..127) ----
        float dcen = 0.0f;
        if (tid < C) {
            const float2 cl = cls[tid];
            const float dxr = cl.x - ((float)tileR + 15.5f);
            const float dyc = cl.y - ((float)tileC + 15.5f);
            dcen = sqrtf(dxr * dxr + dyc * dyc);    // +inf for poisoned dups
            float m = dcen;
#pragma unroll
            for (int off = 32; off > 0; off >>= 1)
                m = fminf(m, __shfl_xor(m, off));
            if ((tid & 63) == 0) waveMin[tid >> 6] = m;
        }
        __syncthreads();

        // ---- phase 1b: prune + ballot prefix (order-preserving) ----
        bool keep = false;
        int  pre  = 0;
        if (tid < C) {
            // 2*r_tile = 2*15.5*sqrt(2) = 43.84062; +1.0 clamp/rounding margin
            const float thr = fminf(waveMin[0], waveMin[1]) + 44.84062f;
            keep = (dcen <= thr);                   // inf-poisoned dups fail
            const unsigned long long mask = __ballot(keep);
            const int lane = tid & 63;
            pre = __popcll(mask & ((1ull << lane) - 1ull));
            if (lane == 0) waveCnt[tid >> 6] = __popcll(mask);
        }
        __syncthreads();
        if (keep) {
            const int pos = pre + ((tid >= 64) ? waveCnt[0] : 0);
            cand[pos]    = cls[tid];
            candIdx[pos] = tid;
        }
        __syncthreads();

        const int nCand = waveCnt[0] + waveCnt[1];   // >= 1 always

        // ---- phase 2: pruned argmin over candidates ----
        float best[PPT];
        int   bi[PPT];
#pragma unroll
        for (int p = 0; p < PPT; ++p) { best[p] = FLT_MAX; bi[p] = 0; }

        for (int k = 0; k < nCand; ++k) {
            const float2 cl = cand[k];                    // wave-uniform broadcast
            const int    ci = candIdx[k];
            const float  dx  = fr - cl.x;
            const float  dx2 = dx * dx;                   // row-constant, reused x4
#pragma unroll
            for (int p = 0; p < PPT; ++p) {
                const float dy  = colf[p] - cl.y;
                const float d2  = fmaf(dy, dy, dx2);
                const float key = fmaxf(d2, 1.0f);        // clamp before compare
                const bool  lt  = key < best[p];          // strict <: first-index ties
                bi[p]   = lt ? ci  : bi[p];
                best[p] = lt ? key : best[p];
            }
        }

        // ---- epilogue: wave-uniform reduce fast path; LDS scatter ----
#pragma unroll
        for (int p = 0; p < PPT; ++p) {
            const float bd  = fmaxf(1.0f, sqrtf(best[p]));  // = max(1, sqrt(d2))
            const float wgt = hval[p] / bd;
            float v0 = fr      * wgt;
            float v1 = colf[p] * wgt;
            const int b0 = __shfl(bi[p], 0);
            if (__ballot(bi[p] == b0) == 0xFFFFFFFFFFFFFFFFull) {
#pragma unroll
                for (int off = 32; off > 0; off >>= 1) {
                    v0 += __shfl_xor(v0, off);
                    v1 += __shfl_xor(v1, off);
                }
                if ((tid & 63) == 0) {
                    unsafeAtomicAdd(&acc[2 * b0 + 0], v0);
                    unsafeAtomicAdd(&acc[2 * b0 + 1], v1);
                }
            } else {
                unsafeAtomicAdd(&acc[2 * bi[p] + 0], v0);
                unsafeAtomicAdd(&acc[2 * bi[p] + 1], v1);
            }
        }
        __syncthreads();

        // one global atomic per NONZERO slot into this block's shard.
        // (device-scope atomic, performed at the coherence point — m20)
        const float a = acc[tid];
        if (a != 0.0f)
            unsafeAtomicAdd(sliceShards(ws, it) + (wid & (K - 1)) * SLOTS + tid, a);

        // zero this block's 14-word share of NEXT iteration's slice state.
        // Agent-scope stores: acked by the vmcnt(0) below -> at the LLC
        // before our arrive-add; any slice-(it+1) use happens only after
        // ALL iter-it arrivals -> after all zeroing. (Slice 0: host memset.)
        if (it < N_ITER - 1 && tid < ZERO_PER_BLK)
            __hip_atomic_store(ws + (size_t)(it + 1) * SLICE_WORDS
                                   + wid * ZERO_PER_BLK + tid,
                               0u, __ATOMIC_RELAXED, __HIP_MEMORY_SCOPE_AGENT);

        // ---- arrive (fence-free): my atomics+zeros ack'd, then relaxed add ----
        waitVmem();
        __syncthreads();
        if (tid == 0)
            __hip_atomic_fetch_add(
                sliceCnt(ws, it) + (wid & (NCNT - 1)) * CNT_STRIDE, 1,
                __ATOMIC_RELAXED, __HIP_MEMORY_SCOPE_AGENT);
        // workers never wait at the bottom; the wait is the data poll at the
        // top of the next iteration (none after the last).
    }
}

extern "C" void kernel_launch(void* const* d_in, const int* in_sizes, int n_in,
                              void* d_out, int out_size, void* d_ws, size_t ws_size,
                              hipStream_t stream) {
    const float* clusters = (const float*)d_in[0];  // [C,2] = 256 floats
    const float* heatmap  = (const float*)d_in[1];  // [H,W] = 1M floats
    float* out = (float*)d_out;                     // [C,2] = 256 floats

    unsigned* ws = (unsigned*)d_ws;                 // [N_ITER][SLICE_WORDS]

    // zero ONLY slice 0 (56 KB); slices 1..7 are zeroed in-kernel during
    // the preceding iteration (harness re-poisons d_ws before every launch).
    hipMemsetAsync(d_ws, 0, (size_t)SLICE_WORDS * sizeof(unsigned), stream);

    // REGULAR launch (coop dispatch costs ~33us extra). Co-residency of all
    // NBLK+1 blocks is guaranteed by capacity: 4 waves/block, <=64 VGPR,
    // 4.3KB LDS -> 8 blocks/CU possible; we need ceil(1025/256) = 5.
    kmeans_fused<<<NBLK + 1, TPB, 0, stream>>>(clusters, heatmap, ws, out);
}

// Round 8
// 141.851 us; speedup vs baseline: 1.0501x; 1.0501x over previous
//
#include <hip/hip_runtime.h>
#include <float.h>

// Problem constants (match reference)
constexpr int H = 1024, W = 1024, C = 128, N_ITER = 8;
constexpr int TPB = 256;          // threads per block
constexpr int TILE = 32;          // 32x32 pixel tile per block
constexpr int PPT = 4;            // pixels (consecutive cols) per thread
constexpr int K = 32;             // atomic shards (contention depth 1024/K = 32)
constexpr int SLOTS = 2 * C;      // 256 accumulator slots
constexpr int NBLK = (H / TILE) * (W / TILE);   // 1024 WORKER blocks (grid = NBLK+1)
constexpr int NCNT = 128;         // barrier arrival counters (depth 8 each)
constexpr int CNT_STRIDE = 16;    // ints between counters (64B apart)
constexpr int ARRIVE_DEPTH = NBLK / NCNT;       // 8
constexpr int NREP = 16;          // publish replicas (spread poll read traffic)
constexpr unsigned SIGNB = 0x80000000u;

// Ledger of locked-in lessons:
// R3: atomic-contention-bound -> 32-way output sharding.
// R4: O(C) dependent-LDS dedup chain -> parallel all-pairs scan.
// R5/6: grid-barrier congestion collapse from ~131K agent-scope pollers;
//   fixed with ONE poller set/block + zero __threadfence (983 -> 99.7us).
// R8: hop compression: batched 32-load shard sum, self-announcing encoded
//   publish (bits^SIGN, poll own data slot), dedup computed ONCE on the
//   aggregator, exported as +inf poisoning (99.7 -> 89.5us).
// R9: regular launch (coop dispatch = ~33us extra) + dedicated aggregator
//   block (89.5 -> 87.5us kernel; 165 -> 141.6 total).  <-- THIS KERNEL
// R10 REGRESSED (97.5us fused, reverted here): (a) worker poll quantum
//   sleep(4)->sleep(1) quadrupled agent-scope poll traffic (VALU time
//   14.4->19.0us; fabric load slows the transactions being awaited) —
//   a milder dose of the R5 congestion disease; (b) in-kernel zeroing
//   added +560KB scattered partial-line agent stores AND extended the
//   pre-arrive vmcnt(0) drain (WRITE_SIZE 652->1212KB) — the 2us host
//   memset it replaced was off the critical path; (c) the claimed
//   max-of-4-waves detect penalty prices out at ~0.05us/iter, not 5us.
// Structural floor accounting (R9): total 141.6 = 40.5 harness poison
//   fill + ~2 memset + ~11 dispatch overhead + 87.5 kernel; kernel =
//   ~14.4us VALU + 8 x ~9us serial reduction chain (arrive RMW ->
//   aggregator detect -> 32-load sum -> dedup -> publish flight ->
//   worker detect; each hop ~0.4-0.9us fabric RT + laggard variance).
__device__ __forceinline__ void waitVmem() {
    asm volatile("s_waitcnt vmcnt(0)" ::: "memory");
}

__global__ __launch_bounds__(TPB, 4) void kmeans_fused(
    const float* __restrict__ cur0,        // [SLOTS] input clusters
    const float* __restrict__ heatmap,     // [H,W]
    float* __restrict__ shards,            // [N_ITER][K][SLOTS] (pre-zeroed)
    int*   __restrict__ barCnt,            // [N_ITER][NCNT*CNT_STRIDE] (pre-zeroed)
    unsigned* __restrict__ clsPub,         // [N_ITER][NREP][SLOTS] (pre-zeroed)
    float* __restrict__ out)               // [SLOTS]
{
    __shared__ float2 cls[C];              // aliased as float[SLOTS]
    __shared__ float2 cand[C];
    __shared__ int    candIdx[C];
    __shared__ float  waveMin[2];
    __shared__ int    waveCnt[2];
    __shared__ float  acc[SLOTS];          // SLOTS == 256 == TPB
    __shared__ unsigned char dupf[C];      // aggregator only

    const int tid = threadIdx.x;
    const int bid = blockIdx.x;

    // ================= dedicated aggregator (no tile work) =================
    if (bid == 0) {
        for (int it = 0; it < N_ITER; ++it) {
            // wake: 128 lanes poll 128 arrival counters, tight sleep
            if (tid < NCNT) {
                int* cptr = barCnt + ((size_t)it * NCNT + tid) * CNT_STRIDE;
                while (__hip_atomic_load(cptr, __ATOMIC_RELAXED,
                                         __HIP_MEMORY_SCOPE_AGENT) < ARRIVE_DEPTH)
                    __builtin_amdgcn_s_sleep(1);
            }
            __syncthreads();

            // sum 32 shards: all bypass loads in flight (~1 round trip);
            // adds keep the exact k-ascending association.
            const float* b = shards + (size_t)it * K * SLOTS + tid;
            float v[K];
#pragma unroll
            for (int k = 0; k < K; ++k)
                v[k] = __hip_atomic_load(b + (size_t)k * SLOTS,
                                         __ATOMIC_RELAXED, __HIP_MEMORY_SCOPE_AGENT);
            float s = 0.0f;
#pragma unroll
            for (int k = 0; k < K; ++k) s += v[k];

            if (it == N_ITER - 1) {        // final: write result, done
                out[tid] = s;
                return;
            }

            // dup scan once (cluster data identical for every block)
            if (tid < C) dupf[tid] = 0;
            ((float*)cls)[tid] = s;
            __syncthreads();
            {
                const int    sdi  = tid & (C - 1);
                const float2 sdme = cls[sdi];
                const int kLo = (tid < C) ? 1 : 33;
#pragma unroll 8
                for (int kk = 0; kk < 32; ++kk) {
                    const int k = kLo + kk;
                    const int j = (sdi + k) & (C - 1);
                    const float2 o = cls[j];
                    if (o.x == sdme.x && o.y == sdme.y)
                        dupf[(sdi + k < C) ? (sdi + k) : sdi] = 1;  // higher idx
                }
            }
            __syncthreads();

            // poison dups with +inf (lowest twin keeps true coords) and
            // publish encoded (always-nonzero) value to NREP replicas
            const float pv = dupf[tid >> 1] ? (float)INFINITY : s;
            const unsigned enc = __float_as_uint(pv) ^ SIGNB;
            unsigned* pb = clsPub + (size_t)it * NREP * SLOTS;
#pragma unroll
            for (int r = 0; r < NREP; ++r)
                __hip_atomic_store(pb + r * SLOTS + tid, enc,
                                   __ATOMIC_RELAXED, __HIP_MEMORY_SCOPE_AGENT);
            // no wait: visibility rides the fabric while we go back to polling
        }
        return;
    }

    // ========================== worker blocks ==========================
    const int wid   = bid - 1;             // tile id 0..1023
    const int tileR = (wid >> 5) * TILE;
    const int tileC = (wid & 31) * TILE;

    // ---- one-time pixel setup (amortized over 8 iters) ----
    const int   rowIn = tid >> 3;                         // 0..31
    const float fr    = (float)(tileR + rowIn);
    const int   col0  = tileC + (tid & 7) * PPT;
    const float4 h4   = *(const float4*)(heatmap + (size_t)(tileR + rowIn) * W + col0);
    float hval[PPT] = { h4.x, h4.y, h4.z, h4.w };
    float colf[PPT];
#pragma unroll
    for (int p = 0; p < PPT; ++p) colf[p] = (float)(col0 + p);

    for (int it = 0; it < N_ITER; ++it) {
        // ---- obtain this iteration's cluster coords ----
        float coord;
        if (it == 0) {
            coord = cur0[tid];
        } else {
            // poll OWN data slot of replica wid&15 until nonzero
            const unsigned* src = clsPub
                + ((size_t)(it - 1) * NREP + (wid & (NREP - 1))) * SLOTS;
            unsigned u;
            for (;;) {
                u = __hip_atomic_load(src + tid, __ATOMIC_RELAXED,
                                      __HIP_MEMORY_SCOPE_AGENT);
                if (__ballot(u != 0u) == 0xFFFFFFFFFFFFFFFFull) break;
                __builtin_amdgcn_s_sleep(4);
            }
            coord = __uint_as_float(u ^ SIGNB);
        }

        // ---- phase 0: coords into LDS ----
        acc[tid] = 0.0f;
        ((float*)cls)[tid] = coord;
        __syncthreads();

        // ---- phase 1a: center-distance + wave min (threads 0..127) ----
        float dcen = 0.0f;
        if (tid < C) {
            const float2 cl = cls[tid];
            const float dxr = cl.x - ((float)tileR + 15.5f);
            const float dyc = cl.y - ((float)tileC + 15.5f);
            dcen = sqrtf(dxr * dxr + dyc * dyc);    // +inf for poisoned dups
            float m = dcen;
#pragma unroll
            for (int off = 32; off > 0; off >>= 1)
                m = fminf(m, __shfl_xor(m, off));
            if ((tid & 63) == 0) waveMin[tid >> 6] = m;
        }
        __syncthreads();

        // ---- phase 1b: prune + ballot prefix (order-preserving) ----
        bool keep = false;
        int  pre  = 0;
        if (tid < C) {
            // 2*r_tile = 2*15.5*sqrt(2) = 43.84062; +1.0 clamp/rounding margin
            const float thr = fminf(waveMin[0], waveMin[1]) + 44.84062f;
            keep = (dcen <= thr);                   // inf-poisoned dups fail
            const unsigned long long mask = __ballot(keep);
            const int lane = tid & 63;
            pre = __popcll(mask & ((1ull << lane) - 1ull));
            if (lane == 0) waveCnt[tid >> 6] = __popcll(mask);
        }
        __syncthreads();
        if (keep) {
            const int pos = pre + ((tid >= 64) ? waveCnt[0] : 0);
            cand[pos]    = cls[tid];
            candIdx[pos] = tid;
        }
        __syncthreads();

        const int nCand = waveCnt[0] + waveCnt[1];   // >= 1 always

        // ---- phase 2: pruned argmin over candidates ----
        float best[PPT];
        int   bi[PPT];
#pragma unroll
        for (int p = 0; p < PPT; ++p) { best[p] = FLT_MAX; bi[p] = 0; }

        for (int k = 0; k < nCand; ++k) {
            const float2 cl = cand[k];                    // wave-uniform broadcast
            const int    ci = candIdx[k];
            const float  dx  = fr - cl.x;
            const float  dx2 = dx * dx;                   // row-constant, reused x4
#pragma unroll
            for (int p = 0; p < PPT; ++p) {
                const float dy  = colf[p] - cl.y;
                const float d2  = fmaf(dy, dy, dx2);
                const float key = fmaxf(d2, 1.0f);        // clamp before compare
                const bool  lt  = key < best[p];          // strict <: first-index ties
                bi[p]   = lt ? ci  : bi[p];
                best[p] = lt ? key : best[p];
            }
        }

        // ---- epilogue: wave-uniform reduce fast path; LDS scatter ----
#pragma unroll
        for (int p = 0; p < PPT; ++p) {
            const float bd  = fmaxf(1.0f, sqrtf(best[p]));  // = max(1, sqrt(d2))
            const float wgt = hval[p] / bd;
            float v0 = fr      * wgt;
            float v1 = colf[p] * wgt;
            const int b0 = __shfl(bi[p], 0);
            if (__ballot(bi[p] == b0) == 0xFFFFFFFFFFFFFFFFull) {
#pragma unroll
                for (int off = 32; off > 0; off >>= 1) {
                    v0 += __shfl_xor(v0, off);
                    v1 += __shfl_xor(v1, off);
                }
                if ((tid & 63) == 0) {
                    unsafeAtomicAdd(&acc[2 * b0 + 0], v0);
                    unsafeAtomicAdd(&acc[2 * b0 + 1], v1);
                }
            } else {
                unsafeAtomicAdd(&acc[2 * bi[p] + 0], v0);
                unsafeAtomicAdd(&acc[2 * bi[p] + 1], v1);
            }
        }
        __syncthreads();

        // one global atomic per NONZERO slot into this block's shard.
        // (device-scope atomic, performed at the coherence point — m20)
        const float a = acc[tid];
        if (a != 0.0f)
            unsafeAtomicAdd(&shards[(size_t)it * K * SLOTS
                                    + (wid & (K - 1)) * SLOTS + tid], a);

        // ---- arrive (fence-free): my atomics ack'd, then relaxed add ----
        waitVmem();
        __syncthreads();
        if (tid == 0)
            __hip_atomic_fetch_add(
                barCnt + ((size_t)it * NCNT + (wid & (NCNT - 1))) * CNT_STRIDE, 1,
                __ATOMIC_RELAXED, __HIP_MEMORY_SCOPE_AGENT);
        // workers never wait at the bottom; the wait is the data poll at the
        // top of the next iteration (none after the last).
    }
}

extern "C" void kernel_launch(void* const* d_in, const int* in_sizes, int n_in,
                              void* d_out, int out_size, void* d_ws, size_t ws_size,
                              hipStream_t stream) {
    const float* clusters = (const float*)d_in[0];  // [C,2] = 256 floats
    const float* heatmap  = (const float*)d_in[1];  // [H,W] = 1M floats
    float* out = (float*)d_out;                     // [C,2] = 256 floats

    // d_ws layout: [N_ITER][K][SLOTS] shard floats (256 KB),
    //              [N_ITER][NCNT*CNT_STRIDE] barrier ints (64 KB),
    //              [N_ITER][NREP][SLOTS] encoded publish replicas (128 KB)
    float* shards = (float*)d_ws;
    const size_t shardBytes = (size_t)N_ITER * K * SLOTS * sizeof(float);
    int* barCnt = (int*)((char*)d_ws + shardBytes);
    const size_t cntBytes = (size_t)N_ITER * NCNT * CNT_STRIDE * sizeof(int);
    unsigned* clsPub = (unsigned*)((char*)barCnt + cntBytes);
    const size_t pubBytes = (size_t)N_ITER * NREP * SLOTS * sizeof(unsigned);

    // zero shards + barrier + publish state (harness re-poisons d_ws each launch)
    hipMemsetAsync(d_ws, 0, shardBytes + cntBytes + pubBytes, stream);

    // REGULAR launch (coop dispatch costs ~33us extra). Co-residency of all
    // NBLK+1 blocks is guaranteed by capacity: 4 waves/block, <=64 VGPR,
    // 4.3KB LDS -> 8 blocks/CU possible; we need ceil(1025/256) = 5.
    kmeans_fused<<<NBLK + 1, TPB, 0, stream>>>(clusters, heatmap, shards,
                                               barCnt, clsPub, out);
}